// Round 6
// baseline (208.748 us; speedup 1.0000x reference)
//
#include <hip/hip_runtime.h>

// CSA bf16-MFMA pipeline v12. B=4 H=W=128 C=128 heads=4 K2=9, hd=32.
// v11 + att restructure: w_qkv pre-permuted to per-lane frag order (wqb2),
// loaded straight from global (L2-hot) -> weight staging phase + 1 barrier/h
// removed; attile double-buffered aliasing dead x-stage buffer -> store
// overlaps softmax; LDS 65->44.5 KB -> 3 blocks/CU (launch_bounds(512,6)).
// av_kernel unchanged from v11 (94.5 us, no spill).
// ws: attb[q*4+h][65536][5dw] | wqb2(frag) | wvb2(frag) | wpb2(frag)

typedef short bf16x8 __attribute__((ext_vector_type(8)));
typedef float f32x4  __attribute__((ext_vector_type(4)));
typedef float v2f    __attribute__((ext_vector_type(2)));

#define SCALE 0.17677669529663687f   // hd^-0.5

__device__ __forceinline__ unsigned short f2bf(float f) {   // RNE (weights only)
  unsigned u = __float_as_uint(f);
  u = (u + 0x7fffu + ((u >> 16) & 1u)) >> 16;
  return (unsigned short)u;
}
__device__ __forceinline__ float bf2f(unsigned short s) {
  return __uint_as_float(((unsigned)s) << 16);
}
// pack two f32 -> bf16 pair (round half-up): 2 add + 1 v_perm
__device__ __forceinline__ unsigned pk2bf(float lo, float hi) {
  unsigned a = __float_as_uint(lo) + 0x8000u;
  unsigned b = __float_as_uint(hi) + 0x8000u;
  return __builtin_amdgcn_perm(b, a, 0x07060302u);  // [b.hi16 : a.hi16]
}
__device__ __forceinline__ bf16x8 ld16(const unsigned short* p) {   // 16B-aligned
  union { bf16x8 v; uint4 u; } r;
  r.u = *(const uint4*)p;
  return r.v;
}

// ---------------- K0: fp32 -> bf16 weight conversion + fragment permute ----
// wq -> wqb2[(((h*6+tile)*4+kk)*64+l)][8]: lane l gets out-col=tile*16+(l&15)
//   (zero if >=81), k=kk*32+(l>>4)*8+j  (B-frag order for att MFMA)
// wv -> wvb2[(((q*4+cg)*2+m)*4+kk)*64+l][8]: chan=cg*32+m*16+(l&15) (A-frag)
// wp -> wpb2[((tn*4+kk)*64+l)][8]: col=tn*16+(l&15) (B-frag)
__global__ __launch_bounds__(256) void cvt_kernel(const float* __restrict__ wq,
                                                  const float* __restrict__ wv,
                                                  const float* __restrict__ wp,
                                                  unsigned short* __restrict__ wqb2,
                                                  unsigned short* __restrict__ wvb2,
                                                  unsigned short* __restrict__ wpb2) {
  int i = blockIdx.x * 256 + threadIdx.x;
  if (i >= 26624) return;
  if (i < 6144) {                        // wq frag permute, zero-pad cols 81..95
    int l = i & 63, rest = i >> 6;
    int kk = rest & 3, r2 = rest >> 2;
    int tile = r2 % 6, h = r2 / 6;
    int col = tile * 16 + (l & 15);
    int k0 = kk * 32 + (l >> 4) * 8;
    unsigned short* d = wqb2 + (long)i * 8;
    ushort4 o0 = make_ushort4(0, 0, 0, 0), o1 = make_ushort4(0, 0, 0, 0);
    if (col < 81) {
      const float* s = wq + (long)(h * 81 + col) * 128 + k0;
      float4 a = *(const float4*)s, b = *(const float4*)(s + 4);
      o0.x = f2bf(a.x); o0.y = f2bf(a.y); o0.z = f2bf(a.z); o0.w = f2bf(a.w);
      o1.x = f2bf(b.x); o1.y = f2bf(b.y); o1.z = f2bf(b.z); o1.w = f2bf(b.w);
    }
    *(ushort4*)d = o0;
    *(ushort4*)(d + 4) = o1;
    return;
  }
  const float* s;
  unsigned short* d;
  if (i < 24576) {                       // wv fragment permute: 18432 items x 8
    int it = i - 6144;
    int l = it & 63, mk = it >> 6;
    int kk = mk & 3, m = (mk >> 2) & 1, qcg = mk >> 3;   // qcg = q*4+cg
    int cg = qcg & 3, q = qcg >> 2;
    int chan = cg * 32 + m * 16 + (l & 15);
    int k0 = kk * 32 + (l >> 4) * 8;
    s = wv + (long)q * 16384 + chan * 128 + k0;
    d = wvb2 + (long)it * 8;
  } else {                               // wp fragment permute: 2048 items x 8
    int it = i - 24576;
    int l = it & 63, kk = (it >> 6) & 3, tn = it >> 8;
    int col = tn * 16 + (l & 15);
    int k0 = kk * 32 + (l >> 4) * 8;
    s = wp + (long)col * 128 + k0;
    d = wpb2 + (long)it * 8;
  }
  float4 a = *(const float4*)s, b = *(const float4*)(s + 4);
  ushort4 o0, o1;
  o0.x = f2bf(a.x); o0.y = f2bf(a.y); o0.z = f2bf(a.z); o0.w = f2bf(a.w);
  o1.x = f2bf(b.x); o1.y = f2bf(b.y); o1.z = f2bf(b.z); o1.w = f2bf(b.w);
  *(ushort4*)d = o0;
  *(ushort4*)(d + 4) = o1;
}

__device__ __forceinline__ void softmax9(const float* L, unsigned short* attile,
                                         int row, int p) {
  float mx = L[0];
#pragma unroll
  for (int q = 1; q < 9; q++) mx = fmaxf(mx, L[q]);
  float e[9], s = 0.f;
#pragma unroll
  for (int q = 0; q < 9; q++) { e[q] = __expf((L[q] - mx) * SCALE); s += e[q]; }
  float inv = 1.f / s;
#pragma unroll
  for (int q = 0; q < 9; q++) attile[row * 90 + q * 10 + p] = f2bf(e[q] * inv);
}

// ---------------- K1: att = softmax_q(x @ w_qkv^T * scale) ----------------
// Weights from global (frag layout, L2-hot), 2 barriers/h, attile dbuf
// aliased over the dead x-stage buffer, store overlapped with softmax.
__global__ __launch_bounds__(512, 6) void att_kernel(const float* __restrict__ x,
                                                     const unsigned short* __restrict__ wqb2,
                                                     unsigned* __restrict__ attb) {
  __shared__ unsigned short AT[11520];      // 23.0 KB: x-stage [64][136] then attile x2
  __shared__ float lg[64][84];              // 21.5 KB
  const int t = threadIdx.x;
  const long m0 = (long)blockIdx.x * 64;
  // stage x fp32 -> bf16: 64 rows x 32 segs of 4 floats = 2048 items
#pragma unroll
  for (int k = 0; k < 4; k++) {
    int i = t + k * 512;
    int row = i >> 5, seg = i & 31;
    float4 v = *(const float4*)(x + (m0 + row) * 128 + seg * 4);
    *(uint2*)((unsigned*)AT + row * 68 + seg * 2) =
        make_uint2(pk2bf(v.x, v.y), pk2bf(v.z, v.w));
  }
  const int w = t >> 6, lane = t & 63, qd = lane >> 4, l15 = lane & 15;
  const int rw = w & 3, th = w >> 2;          // row-group / tn-half of this wave
  const int sr0 = t / 9, sp0 = t - sr0 * 9;
  const int sr1 = (t + 512) / 9, sp1 = (t + 512) - sr1 * 9;
  __syncthreads();
  bf16x8 af[4];
#pragma unroll
  for (int kk = 0; kk < 4; kk++)
    af[kk] = ld16(AT + (rw * 16 + l15) * 136 + kk * 32 + qd * 8);
  const unsigned short* pwb = wqb2 + lane * 8;
  unsigned* ATdw = (unsigned*)AT;

#define STORE_ATT(hh)                                                           \
  { const unsigned* sb = ATdw + ((hh)&1) * 2880;                                \
    _Pragma("unroll") for (int k = 0; k < 6; k++) {                             \
      int i = t + k * 512;                                                      \
      if (i < 2880) {                                                           \
        int q = i / 320, rem = i - q * 320, n = rem / 5, j = rem - n * 5;       \
        attb[((size_t)(q * 4 + (hh)) * 65536 + m0 + n) * 5 + j] =               \
            sb[n * 45 + q * 5 + j];                                             \
      }                                                                         \
    } }

  for (int h = 0; h < 4; h++) {
    // ---- MFMA: B-frags straight from global (L2/L1-hot), regs only ----
    f32x4 acc[3] = {};
#pragma unroll
    for (int kk = 0; kk < 4; kk++)
#pragma unroll
      for (int tn = 0; tn < 3; tn++) {
        bf16x8 bf = *(const bf16x8*)(pwb + ((h * 6 + th * 3 + tn) * 4 + kk) * 512);
        acc[tn] = __builtin_amdgcn_mfma_f32_16x16x32_bf16(af[kk], bf, acc[tn], 0, 0, 0);
      }
    __syncthreads();                        // barS: softmax(h-1) done (lg+attile free)
#pragma unroll
    for (int tn = 0; tn < 3; tn++)
#pragma unroll
      for (int r = 0; r < 4; r++) {
        int col = (th * 3 + tn) * 16 + l15;
        if (col < 81) lg[rw * 16 + qd * 4 + r][col] = acc[tn][r];
      }
    __syncthreads();                        // barL: lg ready
    if (h > 0) STORE_ATT(h - 1)             // overlaps softmax(h)
    unsigned short* attile = AT + (h & 1) * 5760;
    softmax9(&lg[sr0][sp0 * 9], attile, sr0, sp0);
    if (t < 64) softmax9(&lg[sr1][sp1 * 9], attile, sr1, sp1);
  }
  __syncthreads();
  STORE_ATT(3)
}

// ---------------- K2: fused V-MFMA + fold + proj (unchanged v11) ----------
__global__ __launch_bounds__(512, 4) void av_kernel(const float* __restrict__ x,
                                                    const unsigned short* __restrict__ wvb2,
                                                    const unsigned* __restrict__ attb,
                                                    const unsigned short* __restrict__ wpb2,
                                                    float* __restrict__ out) {
  __shared__ unsigned short A[144 * 136];   // 39.2 KB : x halo 12x12 ; yb alias for proj
  __shared__ unsigned short S[100 * 136];   // 27.2 KB : V_q (channel shorts per loc row)
  __shared__ unsigned aLs[2400];            // 9.6 KB  : att [h][100][6 dw]
  const int t = threadIdx.x;
  const int bb = blockIdx.z;
  const int r0 = blockIdx.y * 8, c0 = blockIdx.x * 8;
  const int l15 = t & 15, qd = (t >> 4) & 3, wvi = t >> 6;   // wvi in 0..7
  const int lane = t & 63;
  const int cg = wvi & 3, lp = wvi >> 2;                     // 2-mtile chan-group / loc-half
  const int n = (wvi & 3) * 16 + l15, lr = n >> 3, lc = n & 7;
  const int g = (wvi >> 2) * 4 + qd, head = g >> 1;          // 16-chan group (fold)
  const long nb = (long)bb * 16384;
  unsigned* Sdw = (unsigned*)S;
  unsigned* Adw = (unsigned*)A;

  // V-phase B-operand row bases: tile = lp*4+i (lp=1 has 3 tiles), loc=tile*16+l15
  int xbI[4];
#pragma unroll
  for (int i = 0; i < 4; i++) {
    int tile = lp * 4 + i;
    int ml = tile < 7 ? tile * 16 + l15 : 0;          // 0..111
    xbI[i] = (ml / 10) * 12 + (ml % 10) + 13;
  }

  // ---- stage x halo 12x12 fp32 -> bf16 : 144 rows x 32 segs = 4608 ----
#pragma unroll
  for (int k = 0; k < 9; k++) {
    int i = t + k * 512;
    int row = i >> 5, seg = i & 31;
    int gr = r0 - 2 + row / 12, gc = c0 - 2 + row % 12;
    float4 v = make_float4(0.f, 0.f, 0.f, 0.f);
    if (gr >= 0 && gr < 128 && gc >= 0 && gc < 128)
      v = *(const float4*)(x + (nb + gr * 128 + gc) * 128 + seg * 4);
    *(uint2*)(Adw + row * 68 + seg * 2) = make_uint2(pk2bf(v.x, v.y), pk2bf(v.z, v.w));
  }

  // attb load/scatter decomposition, hoisted out of the q loop
  int aoff[4], aidx[4];
#pragma unroll
  for (int k = 0; k < 4; k++) {
    int i = t + k * 512;
    if (i < 2000) {
      int hh = i / 500, rem = i - hh * 500, row = rem / 5, j5 = rem - row * 5;
      int gr = r0 - 1 + row / 10, gc = c0 - 1 + row % 10;
      aidx[k] = hh * 600 + row * 6 + j5;
      aoff[k] = (gr >= 0 && gr < 128 && gc >= 0 && gc < 128)
                    ? (int)(((size_t)hh * 65536 + nb + gr * 128 + gc) * 5 + j5)
                    : -1;
    } else { aidx[k] = -1; aoff[k] = -1; }
  }
  // w_v A-frags: coalesced per-lane fragment layout (see cvt)
  const unsigned short* pwv = wvb2 + cg * 4096 + lane * 8;

  v2f y2[8];
#pragma unroll
  for (int i = 0; i < 8; i++) y2[i] = (v2f){0.f, 0.f};

  unsigned avv[4];
  bf16x8 wvf[2][4];                         // [mtile][kk] : 32 chans of w_v

#define LOAD_A(qq)                                                              \
  { _Pragma("unroll") for (int k = 0; k < 4; k++)                               \
      avv[k] = (aoff[k] >= 0) ? attb[aoff[k] + (qq) * 1310720] : 0u; }
#define LOAD_WV(qq)                                                             \
  { _Pragma("unroll") for (int m = 0; m < 2; m++)                               \
    _Pragma("unroll") for (int kk = 0; kk < 4; kk++)                            \
      wvf[m][kk] = *(const bf16x8*)(pwv + (size_t)(qq) * 16384 +                \
                                    (m * 4 + kk) * 512); }

  LOAD_A(0)
  LOAD_WV(0)

  for (int q = 0; q < 9; q++) {
    const int qoff = (q / 3) * 12 + (q % 3) - 13;
    __syncthreads();                        // fold(q-1) readers done

    // att regs -> aLs [h][row][6dw]
#pragma unroll
    for (int k = 0; k < 4; k++)
      if (aidx[k] >= 0) aLs[aidx[k]] = avv[k];

    // ---- V_q^T via 16x16x32 MFMA: D[row=chan][col=loc] ----
    // wave = 32 chans (cg) x loc-half (lp); one B-read feeds 2 m-MFMAs
#pragma unroll
    for (int i = 0; i < 4; i++) {
      const int tile = lp * 4 + i;
      if (tile < 7) {                       // lp=1 covers tiles 4..6
        int xr = xbI[i] + qoff;
        xr = xr > 143 ? 143 : xr;           // pad locs (ml>=100) clamp
        bf16x8 bx[4];
#pragma unroll
        for (int kk = 0; kk < 4; kk++)
          bx[kk] = ld16(A + xr * 136 + kk * 32 + qd * 8);
        f32x4 acc[2];
#pragma unroll
        for (int m = 0; m < 2; m++) acc[m] = (f32x4){0.f, 0.f, 0.f, 0.f};
#pragma unroll
        for (int kk = 0; kk < 4; kk++)
#pragma unroll
          for (int m = 0; m < 2; m++)
            acc[m] = __builtin_amdgcn_mfma_f32_16x16x32_bf16(wvf[m][kk], bx[kk],
                                                             acc[m], 0, 0, 0);
        int loc = tile * 16 + l15;
        if (loc < 100) {
#pragma unroll
          for (int m = 0; m < 2; m++)       // chans cg*32+m*16+qd*4 .. +3
            *(uint2*)(Sdw + loc * 68 + cg * 16 + m * 8 + qd * 2) =
                make_uint2(pk2bf(acc[m][0], acc[m][1]),
                           pk2bf(acc[m][2], acc[m][3]));
        }
      }
    }
    __syncthreads();
    if (q < 8) { LOAD_A(q + 1) LOAD_WV(q + 1) }   // overlap with fold

    // ---- fold: y[n, c(g)] += att[n',head,p,q] * V_q[n'] ; 2 x b128 per p ----
    const unsigned short* aS = (const unsigned short*)aLs;
    const int mlb = lr * 10 + lc + 11;
#pragma unroll
    for (int p = 0; p < 9; p++) {
      const int ml = mlb + (1 - p / 3) * 10 + (1 - p % 3);
      const float a = bf2f(aS[head * 1200 + ml * 12 + p]);
      const v2f a2 = {a, a};
      const uint4* Sr = (const uint4*)(Sdw + ml * 68 + g * 8);
#pragma unroll
      for (int v4 = 0; v4 < 2; v4++) {
        const uint4 u = Sr[v4];
        v2f xv;
        const int yi = v4 * 4;
        xv.x = __uint_as_float(u.x << 16); xv.y = __uint_as_float(u.x & 0xffff0000u);
        y2[yi + 0] += a2 * xv;
        xv.x = __uint_as_float(u.y << 16); xv.y = __uint_as_float(u.y & 0xffff0000u);
        y2[yi + 1] += a2 * xv;
        xv.x = __uint_as_float(u.z << 16); xv.y = __uint_as_float(u.z & 0xffff0000u);
        y2[yi + 2] += a2 * xv;
        xv.x = __uint_as_float(u.w << 16); xv.y = __uint_as_float(u.w & 0xffff0000u);
        y2[yi + 3] += a2 * xv;
      }
    }
  }

  // ---- proj: out = y @ wp^T (yb aliases A) ----
  __syncthreads();
  unsigned short* yb = A;
  {
    uint4 pk[2];
#pragma unroll
    for (int v4 = 0; v4 < 2; v4++) {
      pk[v4].x = pk2bf(y2[v4 * 4 + 0].x, y2[v4 * 4 + 0].y);
      pk[v4].y = pk2bf(y2[v4 * 4 + 1].x, y2[v4 * 4 + 1].y);
      pk[v4].z = pk2bf(y2[v4 * 4 + 2].x, y2[v4 * 4 + 2].y);
      pk[v4].w = pk2bf(y2[v4 * 4 + 3].x, y2[v4 * 4 + 3].y);
    }
    uint4* dst = (uint4*)(Adw + n * 68 + g * 8);
    dst[0] = pk[0]; dst[1] = pk[1];
  }
  __syncthreads();
  f32x4 pacc[4] = {};
#pragma unroll
  for (int kk = 0; kk < 4; kk++) {
    bf16x8 afr = ld16(yb + ((wvi & 3) * 16 + l15) * 136 + kk * 32 + qd * 8);
#pragma unroll
    for (int tn = 0; tn < 4; tn++) {
      bf16x8 bfr = *(const bf16x8*)(wpb2 + (((wvi >> 2) * 4 + tn) * 4 + kk) * 512 +
                                    lane * 8);
      pacc[tn] = __builtin_amdgcn_mfma_f32_16x16x32_bf16(afr, bfr, pacc[tn], 0, 0, 0);
    }
  }
#pragma unroll
  for (int tn = 0; tn < 4; tn++)
#pragma unroll
    for (int r = 0; r < 4; r++) {
      int nl = (wvi & 3) * 16 + qd * 4 + r;
      int col = ((wvi >> 2) * 4 + tn) * 16 + l15;
      out[(nb + (r0 + (nl >> 3)) * 128 + (c0 + (nl & 7))) * 128 + col] = pacc[tn][r];
    }
}

extern "C" void kernel_launch(void* const* d_in, const int* in_sizes, int n_in,
                              void* d_out, int out_size, void* d_ws, size_t ws_size,
                              hipStream_t stream) {
  const float* x  = (const float*)d_in[0];
  const float* wq = (const float*)d_in[1];
  const float* wv = (const float*)d_in[2];
  const float* wp = (const float*)d_in[3];
  char* w = (char*)d_ws;
  unsigned*       attb = (unsigned*)w;                        // 47,185,920 B
  unsigned short* wqb2 = (unsigned short*)(w + 47185920);     // 98,304 B (frag)
  unsigned short* wvb2 = wqb2 + 49152;                        // 294,912 B (frag)
  unsigned short* wpb2 = wvb2 + 147456;                       // 32,768 B (frag)

  cvt_kernel<<<104, 256, 0, stream>>>(wq, wv, wp, wqb2, wvb2, wpb2);
  att_kernel<<<1024, 512, 0, stream>>>(x, wqb2, attb);
  dim3 g3(16, 16, 4);
  av_kernel<<<g3, 512, 0, stream>>>(x, wvb2, attb, wpb2, (float*)d_out);
}

// Round 7
// 189.918 us; speedup vs baseline: 1.0991x; 1.0991x over previous
//
#include <hip/hip_runtime.h>

// CSA bf16-MFMA pipeline v13. B=4 H=W=128 C=128 heads=4 K2=9, hd=32.
// v11 + att occupancy fix ONLY: x-stage LDS buffer dropped (af converted
// straight from global fp32, L2-hot, off critical path); LDS 65->47.6 KB
// (Bl 26.1 + lg 21.5) -> 3 blocks/CU via launch_bounds(512,6). Weights stay
// LDS-staged (v12's global-B + 84-reg cap serialized loads -> reverted).
// cvt + av_kernel byte-identical to v11 (190.4/94.4 us proven).
// ws: attb[q*4+h][65536][5dw] | wqb(linear) | wvb2(frag) | wpb2(frag)

typedef short bf16x8 __attribute__((ext_vector_type(8)));
typedef float f32x4  __attribute__((ext_vector_type(4)));
typedef float v2f    __attribute__((ext_vector_type(2)));

#define SCALE 0.17677669529663687f   // hd^-0.5

__device__ __forceinline__ unsigned short f2bf(float f) {   // RNE (weights only)
  unsigned u = __float_as_uint(f);
  u = (u + 0x7fffu + ((u >> 16) & 1u)) >> 16;
  return (unsigned short)u;
}
__device__ __forceinline__ float bf2f(unsigned short s) {
  return __uint_as_float(((unsigned)s) << 16);
}
// pack two f32 -> bf16 pair (round half-up): 2 add + 1 v_perm
__device__ __forceinline__ unsigned pk2bf(float lo, float hi) {
  unsigned a = __float_as_uint(lo) + 0x8000u;
  unsigned b = __float_as_uint(hi) + 0x8000u;
  return __builtin_amdgcn_perm(b, a, 0x07060302u);  // [b.hi16 : a.hi16]
}
__device__ __forceinline__ bf16x8 ld16(const unsigned short* p) {   // 16B-aligned
  union { bf16x8 v; uint4 u; } r;
  r.u = *(const uint4*)p;
  return r.v;
}

// ---------------- K0: fp32 -> bf16 weight conversion + fragment permute ----
// wq: layout unchanged (linear). wv -> wvb2[(((q*4+cg)*2+m)*4+kk)*64+l][8]:
//   lane l gets chan=cg*32+m*16+(l&15), k=kk*32+(l>>4)*8+j  (A-frag order)
// wp -> wpb2[((tn*4+kk)*64+l)][8]: col=tn*16+(l&15), k=kk*32+(l>>4)*8+j
__global__ __launch_bounds__(256) void cvt_kernel(const float* __restrict__ wq,
                                                  const float* __restrict__ wv,
                                                  const float* __restrict__ wp,
                                                  unsigned short* __restrict__ wqb,
                                                  unsigned short* __restrict__ wvb2,
                                                  unsigned short* __restrict__ wpb2) {
  int i = blockIdx.x * 256 + threadIdx.x;
  if (i >= 30848) return;
  if (i < 10368) {                       // wq: 4 floats each, layout unchanged
    long off = (long)i * 4;
    float4 v = *(const float4*)(wq + off);
    ushort4 o;
    o.x = f2bf(v.x); o.y = f2bf(v.y); o.z = f2bf(v.z); o.w = f2bf(v.w);
    *(ushort4*)(wqb + off) = o;
    return;
  }
  const float* s;
  unsigned short* d;
  if (i < 28800) {                       // wv fragment permute: 18432 items x 8
    int it = i - 10368;
    int l = it & 63, mk = it >> 6;
    int kk = mk & 3, m = (mk >> 2) & 1, qcg = mk >> 3;   // qcg = q*4+cg
    int cg = qcg & 3, q = qcg >> 2;
    int chan = cg * 32 + m * 16 + (l & 15);
    int k0 = kk * 32 + (l >> 4) * 8;
    s = wv + (long)q * 16384 + chan * 128 + k0;
    d = wvb2 + (long)it * 8;
  } else {                               // wp fragment permute: 2048 items x 8
    int it = i - 28800;
    int l = it & 63, kk = (it >> 6) & 3, tn = it >> 8;
    int col = tn * 16 + (l & 15);
    int k0 = kk * 32 + (l >> 4) * 8;
    s = wp + (long)col * 128 + k0;
    d = wpb2 + (long)it * 8;
  }
  float4 a = *(const float4*)s, b = *(const float4*)(s + 4);
  ushort4 o0, o1;
  o0.x = f2bf(a.x); o0.y = f2bf(a.y); o0.z = f2bf(a.z); o0.w = f2bf(a.w);
  o1.x = f2bf(b.x); o1.y = f2bf(b.y); o1.z = f2bf(b.z); o1.w = f2bf(b.w);
  *(ushort4*)d = o0;
  *(ushort4*)(d + 4) = o1;
}

__device__ __forceinline__ void softmax9(const float* L, unsigned short* attile,
                                         int row, int p) {
  float mx = L[0];
#pragma unroll
  for (int q = 1; q < 9; q++) mx = fmaxf(mx, L[q]);
  float e[9], s = 0.f;
#pragma unroll
  for (int q = 0; q < 9; q++) { e[q] = __expf((L[q] - mx) * SCALE); s += e[q]; }
  float inv = 1.f / s;
#pragma unroll
  for (int q = 0; q < 9; q++) attile[row * 90 + q * 10 + p] = f2bf(e[q] * inv);
}

// ---------------- K1: att = softmax_q(x @ w_qkv^T * scale) ----------------
// v11 structure; x-stage LDS dropped (af from global), 47.6 KB -> 3 blk/CU.
__global__ __launch_bounds__(512, 6) void att_kernel(const float* __restrict__ x,
                                                     const unsigned short* __restrict__ wqb,
                                                     unsigned* __restrict__ attb) {
  __shared__ unsigned short Bl[96 * 136];   // 26.1 KB: weights; attile aliased
  __shared__ float lg[64][84];              // 21.5 KB
  const int t = threadIdx.x;
  const long m0 = (long)blockIdx.x * 64;
  const int w = t >> 6, lane = t & 63, qd = lane >> 4, l15 = lane & 15;
  const int rw = w & 3, th = w >> 2;          // row-group / tn-half of this wave
  const int sr0 = t / 9, sp0 = t - sr0 * 9;
  const int sr1 = (t + 512) / 9, sp1 = (t + 512) - sr1 * 9;
  // store decomposition: 2880 dwords, hoisted out of h loop
  int dsto[6], srco[6];
#pragma unroll
  for (int k = 0; k < 6; k++) {
    int i = t + k * 512;
    if (i < 2880) {
      int q = i / 320, rem = i - q * 320, n = rem / 5, j = rem - n * 5;
      dsto[k] = (int)(((size_t)(q * 4) * 65536 + m0 + n) * 5 + j);
      srco[k] = n * 45 + q * 5 + j;
    } else { dsto[k] = -1; srco[k] = 0; }
  }
  // af straight from global fp32 (x rows m0..m0+63, L2-hot; 64 B/lane)
  bf16x8 af[4];
  {
    const float* xr = x + (m0 + rw * 16 + l15) * 128 + qd * 8;
#pragma unroll
    for (int kk = 0; kk < 4; kk++) {
      float4 a = *(const float4*)(xr + kk * 32);
      float4 b = *(const float4*)(xr + kk * 32 + 4);
      union { uint4 u; bf16x8 v; } r;
      r.u = make_uint4(pk2bf(a.x, a.y), pk2bf(a.z, a.w),
                       pk2bf(b.x, b.y), pk2bf(b.z, b.w));
      af[kk] = r.v;
    }
  }
  unsigned short* attile = Bl;              // [64][9][10] shorts, aliased
  for (int h = 0; h < 4; h++) {
    __syncthreads();                        // store-readers done / Bl free
#pragma unroll
    for (int k = 0; k < 3; k++) {
      int i = t + k * 512;
      if (i < 1296) {
        int row = i >> 4, seg = i & 15;
        const uint4 v = *(const uint4*)(wqb + (long)(h * 81 + row) * 128 + seg * 8);
        *(uint4*)((unsigned*)Bl + row * 68 + seg * 4) = v;
      }
    }
    __syncthreads();
    f32x4 acc[3] = {};
#pragma unroll
    for (int kk = 0; kk < 4; kk++)
#pragma unroll
      for (int tn = 0; tn < 3; tn++) {
        bf16x8 bf = ld16(Bl + ((th * 3 + tn) * 16 + l15) * 136 + kk * 32 + qd * 8);
        acc[tn] = __builtin_amdgcn_mfma_f32_16x16x32_bf16(af[kk], bf, acc[tn], 0, 0, 0);
      }
#pragma unroll
    for (int tn = 0; tn < 3; tn++)
#pragma unroll
      for (int r = 0; r < 4; r++) {
        int col = (th * 3 + tn) * 16 + l15;
        if (col < 81) lg[rw * 16 + qd * 4 + r][col] = acc[tn][r];
      }
    __syncthreads();
    softmax9(&lg[sr0][sp0 * 9], attile, sr0, sp0);
    if (t < 64) softmax9(&lg[sr1][sp1 * 9], attile, sr1, sp1);
    __syncthreads();
    // q-major coalesced store: attb[(q*4+h)][m0+n][5 dw]
#pragma unroll
    for (int k = 0; k < 6; k++)
      if (dsto[k] >= 0)
        attb[dsto[k] + h * 327680] = ((const unsigned*)attile)[srco[k]];
  }
}

// ---------------- K2: fused V-MFMA + fold + proj (unchanged v11) ----------
__global__ __launch_bounds__(512, 4) void av_kernel(const float* __restrict__ x,
                                                    const unsigned short* __restrict__ wvb2,
                                                    const unsigned* __restrict__ attb,
                                                    const unsigned short* __restrict__ wpb2,
                                                    float* __restrict__ out) {
  __shared__ unsigned short A[144 * 136];   // 39.2 KB : x halo 12x12 ; yb alias for proj
  __shared__ unsigned short S[100 * 136];   // 27.2 KB : V_q (channel shorts per loc row)
  __shared__ unsigned aLs[2400];            // 9.6 KB  : att [h][100][6 dw]
  const int t = threadIdx.x;
  const int bb = blockIdx.z;
  const int r0 = blockIdx.y * 8, c0 = blockIdx.x * 8;
  const int l15 = t & 15, qd = (t >> 4) & 3, wvi = t >> 6;   // wvi in 0..7
  const int lane = t & 63;
  const int cg = wvi & 3, lp = wvi >> 2;                     // 2-mtile chan-group / loc-half
  const int n = (wvi & 3) * 16 + l15, lr = n >> 3, lc = n & 7;
  const int g = (wvi >> 2) * 4 + qd, head = g >> 1;          // 16-chan group (fold)
  const long nb = (long)bb * 16384;
  unsigned* Sdw = (unsigned*)S;
  unsigned* Adw = (unsigned*)A;

  // V-phase B-operand row bases: tile = lp*4+i (lp=1 has 3 tiles), loc=tile*16+l15
  int xbI[4];
#pragma unroll
  for (int i = 0; i < 4; i++) {
    int tile = lp * 4 + i;
    int ml = tile < 7 ? tile * 16 + l15 : 0;          // 0..111
    xbI[i] = (ml / 10) * 12 + (ml % 10) + 13;
  }

  // ---- stage x halo 12x12 fp32 -> bf16 : 144 rows x 32 segs = 4608 ----
#pragma unroll
  for (int k = 0; k < 9; k++) {
    int i = t + k * 512;
    int row = i >> 5, seg = i & 31;
    int gr = r0 - 2 + row / 12, gc = c0 - 2 + row % 12;
    float4 v = make_float4(0.f, 0.f, 0.f, 0.f);
    if (gr >= 0 && gr < 128 && gc >= 0 && gc < 128)
      v = *(const float4*)(x + (nb + gr * 128 + gc) * 128 + seg * 4);
    *(uint2*)(Adw + row * 68 + seg * 2) = make_uint2(pk2bf(v.x, v.y), pk2bf(v.z, v.w));
  }

  // attb load/scatter decomposition, hoisted out of the q loop
  int aoff[4], aidx[4];
#pragma unroll
  for (int k = 0; k < 4; k++) {
    int i = t + k * 512;
    if (i < 2000) {
      int hh = i / 500, rem = i - hh * 500, row = rem / 5, j5 = rem - row * 5;
      int gr = r0 - 1 + row / 10, gc = c0 - 1 + row % 10;
      aidx[k] = hh * 600 + row * 6 + j5;
      aoff[k] = (gr >= 0 && gr < 128 && gc >= 0 && gc < 128)
                    ? (int)(((size_t)hh * 65536 + nb + gr * 128 + gc) * 5 + j5)
                    : -1;
    } else { aidx[k] = -1; aoff[k] = -1; }
  }
  // w_v A-frags: coalesced per-lane fragment layout (see cvt)
  const unsigned short* pwv = wvb2 + cg * 4096 + lane * 8;

  v2f y2[8];
#pragma unroll
  for (int i = 0; i < 8; i++) y2[i] = (v2f){0.f, 0.f};

  unsigned avv[4];
  bf16x8 wvf[2][4];                         // [mtile][kk] : 32 chans of w_v

#define LOAD_A(qq)                                                              \
  { _Pragma("unroll") for (int k = 0; k < 4; k++)                               \
      avv[k] = (aoff[k] >= 0) ? attb[aoff[k] + (qq) * 1310720] : 0u; }
#define LOAD_WV(qq)                                                             \
  { _Pragma("unroll") for (int m = 0; m < 2; m++)                               \
    _Pragma("unroll") for (int kk = 0; kk < 4; kk++)                            \
      wvf[m][kk] = *(const bf16x8*)(pwv + (size_t)(qq) * 16384 +                \
                                    (m * 4 + kk) * 512); }

  LOAD_A(0)
  LOAD_WV(0)

  for (int q = 0; q < 9; q++) {
    const int qoff = (q / 3) * 12 + (q % 3) - 13;
    __syncthreads();                        // fold(q-1) readers done

    // att regs -> aLs [h][row][6dw]
#pragma unroll
    for (int k = 0; k < 4; k++)
      if (aidx[k] >= 0) aLs[aidx[k]] = avv[k];

    // ---- V_q^T via 16x16x32 MFMA: D[row=chan][col=loc] ----
    // wave = 32 chans (cg) x loc-half (lp); one B-read feeds 2 m-MFMAs
#pragma unroll
    for (int i = 0; i < 4; i++) {
      const int tile = lp * 4 + i;
      if (tile < 7) {                       // lp=1 covers tiles 4..6
        int xr = xbI[i] + qoff;
        xr = xr > 143 ? 143 : xr;           // pad locs (ml>=100) clamp
        bf16x8 bx[4];
#pragma unroll
        for (int kk = 0; kk < 4; kk++)
          bx[kk] = ld16(A + xr * 136 + kk * 32 + qd * 8);
        f32x4 acc[2];
#pragma unroll
        for (int m = 0; m < 2; m++) acc[m] = (f32x4){0.f, 0.f, 0.f, 0.f};
#pragma unroll
        for (int kk = 0; kk < 4; kk++)
#pragma unroll
          for (int m = 0; m < 2; m++)
            acc[m] = __builtin_amdgcn_mfma_f32_16x16x32_bf16(wvf[m][kk], bx[kk],
                                                             acc[m], 0, 0, 0);
        int loc = tile * 16 + l15;
        if (loc < 100) {
#pragma unroll
          for (int m = 0; m < 2; m++)       // chans cg*32+m*16+qd*4 .. +3
            *(uint2*)(Sdw + loc * 68 + cg * 16 + m * 8 + qd * 2) =
                make_uint2(pk2bf(acc[m][0], acc[m][1]),
                           pk2bf(acc[m][2], acc[m][3]));
        }
      }
    }
    __syncthreads();
    if (q < 8) { LOAD_A(q + 1) LOAD_WV(q + 1) }   // overlap with fold

    // ---- fold: y[n, c(g)] += att[n',head,p,q] * V_q[n'] ; 2 x b128 per p ----
    const unsigned short* aS = (const unsigned short*)aLs;
    const int mlb = lr * 10 + lc + 11;
#pragma unroll
    for (int p = 0; p < 9; p++) {
      const int ml = mlb + (1 - p / 3) * 10 + (1 - p % 3);
      const float a = bf2f(aS[head * 1200 + ml * 12 + p]);
      const v2f a2 = {a, a};
      const uint4* Sr = (const uint4*)(Sdw + ml * 68 + g * 8);
#pragma unroll
      for (int v4 = 0; v4 < 2; v4++) {
        const uint4 u = Sr[v4];
        v2f xv;
        const int yi = v4 * 4;
        xv.x = __uint_as_float(u.x << 16); xv.y = __uint_as_float(u.x & 0xffff0000u);
        y2[yi + 0] += a2 * xv;
        xv.x = __uint_as_float(u.y << 16); xv.y = __uint_as_float(u.y & 0xffff0000u);
        y2[yi + 1] += a2 * xv;
        xv.x = __uint_as_float(u.z << 16); xv.y = __uint_as_float(u.z & 0xffff0000u);
        y2[yi + 2] += a2 * xv;
        xv.x = __uint_as_float(u.w << 16); xv.y = __uint_as_float(u.w & 0xffff0000u);
        y2[yi + 3] += a2 * xv;
      }
    }
  }

  // ---- proj: out = y @ wp^T (yb aliases A) ----
  __syncthreads();
  unsigned short* yb = A;
  {
    uint4 pk[2];
#pragma unroll
    for (int v4 = 0; v4 < 2; v4++) {
      pk[v4].x = pk2bf(y2[v4 * 4 + 0].x, y2[v4 * 4 + 0].y);
      pk[v4].y = pk2bf(y2[v4 * 4 + 1].x, y2[v4 * 4 + 1].y);
      pk[v4].z = pk2bf(y2[v4 * 4 + 2].x, y2[v4 * 4 + 2].y);
      pk[v4].w = pk2bf(y2[v4 * 4 + 3].x, y2[v4 * 4 + 3].y);
    }
    uint4* dst = (uint4*)(Adw + n * 68 + g * 8);
    dst[0] = pk[0]; dst[1] = pk[1];
  }
  __syncthreads();
  f32x4 pacc[4] = {};
#pragma unroll
  for (int kk = 0; kk < 4; kk++) {
    bf16x8 afr = ld16(yb + ((wvi & 3) * 16 + l15) * 136 + kk * 32 + qd * 8);
#pragma unroll
    for (int tn = 0; tn < 4; tn++) {
      bf16x8 bfr = *(const bf16x8*)(wpb2 + (((wvi >> 2) * 4 + tn) * 4 + kk) * 512 +
                                    lane * 8);
      pacc[tn] = __builtin_amdgcn_mfma_f32_16x16x32_bf16(afr, bfr, pacc[tn], 0, 0, 0);
    }
  }
#pragma unroll
  for (int tn = 0; tn < 4; tn++)
#pragma unroll
    for (int r = 0; r < 4; r++) {
      int nl = (wvi & 3) * 16 + qd * 4 + r;
      int col = ((wvi >> 2) * 4 + tn) * 16 + l15;
      out[(nb + (r0 + (nl >> 3)) * 128 + (c0 + (nl & 7))) * 128 + col] = pacc[tn][r];
    }
}

extern "C" void kernel_launch(void* const* d_in, const int* in_sizes, int n_in,
                              void* d_out, int out_size, void* d_ws, size_t ws_size,
                              hipStream_t stream) {
  const float* x  = (const float*)d_in[0];
  const float* wq = (const float*)d_in[1];
  const float* wv = (const float*)d_in[2];
  const float* wp = (const float*)d_in[3];
  char* w = (char*)d_ws;
  unsigned*       attb = (unsigned*)w;                        // 47,185,920 B
  unsigned short* wqb  = (unsigned short*)(w + 47185920);     // 82,944 B (linear)
  unsigned short* wvb2 = wqb + 41472;                         // 294,912 B (frag)
  unsigned short* wpb2 = wvb2 + 147456;                       // 32,768 B (frag)

  cvt_kernel<<<121, 256, 0, stream>>>(wq, wv, wp, wqb, wvb2, wpb2);
  att_kernel<<<1024, 512, 0, stream>>>(x, wqb, attb);
  dim3 g3(16, 16, 4);
  av_kernel<<<g3, 512, 0, stream>>>(x, wvb2, attb, wpb2, (float*)d_out);
}